// Round 3
// baseline (81.015 us; speedup 1.0000x reference)
//
#include <hip/hip_runtime.h>

// FISM scoring for MI355X (gfx950), R3: two-kernel temporal split.
//
// Rationale: item_table and past_item_table are 256 MB each; L3 is 256 MB.
// Gathering from both concurrently (R2) makes the combined unique working set
// (~286 MB/call) thrash L3, so repeated-row gathers (~32% of draws) miss to
// HBM. Splitting into kernel A (history pooling -> profile, touches only
// past_item_table) and kernel B (scores, touches only item_table) keeps each
// kernel's unique set (~143 MB) L3-resident -> repeats hit L3, and part of
// the set survives across graph replays.
//
// Kernel A writes profile [B,64] f32 into d_ws (ws is ~1 GB, poisoned 0xAA by
// harness; we fully overwrite the 1 MB we use every call -> deterministic).

#define FISM_B       4096
#define FISM_NDOCS   200
#define FISM_HIST    200
#define FISM_NF      64

// ---------------- Kernel A: profile[b,:] = len^-0.5 * sum_h mask*past_emb ----------------
__global__ __launch_bounds__(256, 8) void fism_profile_kernel(
    const int*   __restrict__ past_item_lst,   // [B, HIST]
    const int*   __restrict__ len_past_items,  // [B]
    const float* __restrict__ past_item_table, // [N_ITEMS, 64]
    float*       __restrict__ prof_ws)         // [B, 64]
{
    const int b    = blockIdx.x;
    const int t    = threadIdx.x;
    const int wave = t >> 6;
    const int lane = t & 63;
    const int fgrp = lane & 15;      // owns factors 4*fgrp .. 4*fgrp+3
    const int sub  = lane >> 4;
    const int row  = wave * 4 + sub; // 0..15

    __shared__ int   sPast[FISM_HIST];
    __shared__ float red[4 * 64];

    if (t < FISM_HIST) sPast[t] = past_item_lst[(size_t)b * FISM_HIST + t];
    __syncthreads();

    float4 acc = make_float4(0.f, 0.f, 0.f, 0.f);
    #pragma unroll 4
    for (int i = 0; i < 13; ++i) {
        int h = i * 16 + row;
        if (h < FISM_HIST) {
            int idx = sPast[h];
            if (idx > 0) {
                const float4 v = *(const float4*)(past_item_table + (size_t)idx * FISM_NF + fgrp * 4);
                acc.x += v.x; acc.y += v.y; acc.z += v.z; acc.w += v.w;
            }
        }
    }

    acc.x += __shfl_xor(acc.x, 16); acc.y += __shfl_xor(acc.y, 16);
    acc.z += __shfl_xor(acc.z, 16); acc.w += __shfl_xor(acc.w, 16);
    acc.x += __shfl_xor(acc.x, 32); acc.y += __shfl_xor(acc.y, 32);
    acc.z += __shfl_xor(acc.z, 32); acc.w += __shfl_xor(acc.w, 32);

    if (sub == 0) ((float4*)red)[wave * 16 + fgrp] = acc;
    __syncthreads();

    if (t < FISM_NF) {
        float pooled = red[t] + red[64 + t] + red[128 + t] + red[192 + t];
        float len    = (float)len_past_items[b];
        float coeff  = 1.0f / sqrtf(len);   // len^{-0.5}; sqrtf for tight tolerance
        prof_ws[(size_t)b * FISM_NF + t] = coeff * pooled;  // coalesced 256B/block
    }
}

// ---------------- Kernel B: out[b,d] = dot(profile[b], mask*item_emb) + bias ----------------
__global__ __launch_bounds__(256, 8) void fism_score_kernel(
    const int*   __restrict__ item_lst,        // [B, N_DOCS]
    const float* __restrict__ item_table,      // [N_ITEMS, 64]
    const float* __restrict__ item_bias_table, // [N_ITEMS, 1]
    const float* __restrict__ prof_ws,         // [B, 64]
    float*       __restrict__ out)             // [B, N_DOCS]
{
    const int b    = blockIdx.x;
    const int t    = threadIdx.x;
    const int wave = t >> 6;
    const int lane = t & 63;
    const int fgrp = lane & 15;
    const int sub  = lane >> 4;
    const int row  = wave * 4 + sub;

    __shared__ int   sDocs[FISM_NDOCS];
    __shared__ float sc[FISM_NDOCS];

    if (t < FISM_NDOCS) sDocs[t] = item_lst[(size_t)b * FISM_NDOCS + t];
    __syncthreads();

    // Each group's slice of this row's profile (256B row, L2-resident).
    const float4 pv = ((const float4*)(prof_ws + (size_t)b * FISM_NF))[fgrp];

    #pragma unroll 4
    for (int i = 0; i < 13; ++i) {
        int d = i * 16 + row;
        // d is uniform within each 16-lane shuffle group -> divergence-safe.
        if (d < FISM_NDOCS) {
            int idx = sDocs[d];
            float partial = 0.f;
            if (idx > 0) {
                const float4 v = *(const float4*)(item_table + (size_t)idx * FISM_NF + fgrp * 4);
                partial = v.x * pv.x + v.y * pv.y + v.z * pv.z + v.w * pv.w;
            }
            partial += __shfl_xor(partial, 1);
            partial += __shfl_xor(partial, 2);
            partial += __shfl_xor(partial, 4);
            partial += __shfl_xor(partial, 8);
            if (fgrp == 0) {
                // Bias added unconditionally in the reference (even for id==0).
                sc[d] = partial + item_bias_table[idx];
            }
        }
    }
    __syncthreads();

    if (t < FISM_NDOCS / 4) {
        ((float4*)(out + (size_t)b * FISM_NDOCS))[t] = ((const float4*)sc)[t];
    }
}

extern "C" void kernel_launch(void* const* d_in, const int* in_sizes, int n_in,
                              void* d_out, int out_size, void* d_ws, size_t ws_size,
                              hipStream_t stream) {
    const int*   item_lst        = (const int*)d_in[0];
    const int*   past_item_lst   = (const int*)d_in[1];
    const int*   len_past_items  = (const int*)d_in[2];
    const float* item_table      = (const float*)d_in[3];
    const float* past_item_table = (const float*)d_in[4];
    const float* item_bias_table = (const float*)d_in[5];
    float*       out             = (float*)d_out;
    float*       prof_ws         = (float*)d_ws;   // [B,64] f32 = 1 MB

    fism_profile_kernel<<<FISM_B, 256, 0, stream>>>(
        past_item_lst, len_past_items, past_item_table, prof_ws);
    fism_score_kernel<<<FISM_B, 256, 0, stream>>>(
        item_lst, item_table, item_bias_table, prof_ws, out);
}

// Round 4
// 74.718 us; speedup vs baseline: 1.0843x; 1.0843x over previous
//
#include <hip/hip_runtime.h>

// FISM scoring kernel for MI355X (gfx950). R4 = R2 fused structure (best:
// 76.3us) + phase-2 bias-load hoist.
//
// B=4096 batch rows, N_DOCS=200 candidates, HIST=200 history, F=64 factors.
// One block (256 threads = 4 waves) per batch row; each 16-lane sub-group
// handles one gathered 256B row via float4 loads (1KiB per wave mem inst).
//
// R3's two-kernel temporal split (L3 working-set theory) REGRESSED 76->81us;
// fused is better: phase overlap beats any L3-retention gain.
//
// R4 change: issue the random 4B bias load (fgrp==0 lane) at trip start so
// its ~200-500cy latency hides under the row gather + dot + shuffle reduce,
// instead of sitting as a dependent load after the reduce.

#define FISM_B       4096
#define FISM_NDOCS   200
#define FISM_HIST    200
#define FISM_NF      64

__global__ __launch_bounds__(256, 8) void FISM_55284819034149_kernel(
    const int*   __restrict__ item_lst,        // [B, N_DOCS]
    const int*   __restrict__ past_item_lst,   // [B, HIST]
    const int*   __restrict__ len_past_items,  // [B]
    const float* __restrict__ item_table,      // [N_ITEMS, 64]
    const float* __restrict__ past_item_table, // [N_ITEMS, 64]
    const float* __restrict__ item_bias_table, // [N_ITEMS, 1]
    float*       __restrict__ out)             // [B, N_DOCS]
{
    const int b    = blockIdx.x;
    const int t    = threadIdx.x;
    const int wave = t >> 6;        // 0..3
    const int lane = t & 63;
    const int fgrp = lane & 15;     // factor group: owns factors 4*fgrp .. 4*fgrp+3
    const int sub  = lane >> 4;     // 0..3: row sub-group within the wave
    const int row  = wave * 4 + sub;// 0..15: which gathered row this group owns per trip

    __shared__ int   sPast[FISM_HIST];
    __shared__ int   sDocs[FISM_NDOCS];
    __shared__ float red[4 * 64];   // per-wave pooled partials
    __shared__ float prof[FISM_NF]; // final profile vector
    __shared__ float sc[FISM_NDOCS];// staged scores for coalesced writeback

    // ---------- Stage index lists into LDS (coalesced, removes dependent chain) ----------
    if (t < FISM_HIST)  sPast[t] = past_item_lst[(size_t)b * FISM_HIST + t];
    if (t < FISM_NDOCS) sDocs[t] = item_lst[(size_t)b * FISM_NDOCS + t];
    __syncthreads();

    // ---------- Phase 1: pooled = sum_h mask(past_id>0) * past_item_table[past_id] ----------
    float4 acc = make_float4(0.f, 0.f, 0.f, 0.f);

    #pragma unroll 4
    for (int i = 0; i < 13; ++i) {          // ceil(200/16) trips, 16 rows/block/trip
        int h = i * 16 + row;
        if (h < FISM_HIST) {
            int idx = sPast[h];
            if (idx > 0) {
                const float4 v = *(const float4*)(past_item_table + (size_t)idx * FISM_NF + fgrp * 4);
                acc.x += v.x; acc.y += v.y; acc.z += v.z; acc.w += v.w;
            }
        }
    }

    // Reduce across the 4 sub-groups of this wave (lanes differing in bits 4,5).
    acc.x += __shfl_xor(acc.x, 16); acc.y += __shfl_xor(acc.y, 16);
    acc.z += __shfl_xor(acc.z, 16); acc.w += __shfl_xor(acc.w, 16);
    acc.x += __shfl_xor(acc.x, 32); acc.y += __shfl_xor(acc.y, 32);
    acc.z += __shfl_xor(acc.z, 32); acc.w += __shfl_xor(acc.w, 32);

    if (sub == 0) {
        // lanes 0..15 of each wave hold the wave's pooled sum for factors 4*fgrp..+3
        ((float4*)red)[wave * 16 + fgrp] = acc;
    }
    __syncthreads();

    if (t < FISM_NF) {
        float pooled = red[t] + red[64 + t] + red[128 + t] + red[192 + t];
        float len    = (float)len_past_items[b];
        float coeff  = 1.0f / sqrtf(len);   // len^{-0.5}; sqrtf for tight tolerance
        prof[t] = coeff * pooled;
    }
    __syncthreads();

    // ---------- Phase 2: scores[b,d] = dot(profile, mask*item_table[id]) + bias[id] ----------
    const float4 pv = *(const float4*)(prof + fgrp * 4);

    #pragma unroll 4
    for (int i = 0; i < 13; ++i) {
        int d = i * 16 + row;
        // d is uniform within each 16-lane shuffle group -> divergence-safe.
        if (d < FISM_NDOCS) {
            int idx = sDocs[d];
            // Issue the bias load FIRST so it overlaps the row gather + reduce.
            // (Bias is added unconditionally in the reference, even for id==0.)
            float bias = 0.f;
            if (fgrp == 0) bias = item_bias_table[idx];
            float partial = 0.f;
            if (idx > 0) {
                const float4 v = *(const float4*)(item_table + (size_t)idx * FISM_NF + fgrp * 4);
                partial = v.x * pv.x + v.y * pv.y + v.z * pv.z + v.w * pv.w;
            }
            // Reduce across the 16 lanes of this group.
            partial += __shfl_xor(partial, 1);
            partial += __shfl_xor(partial, 2);
            partial += __shfl_xor(partial, 4);
            partial += __shfl_xor(partial, 8);
            if (fgrp == 0) {
                sc[d] = partial + bias;
            }
        }
    }
    __syncthreads();

    // ---------- Coalesced writeback: 200 floats = 50 float4 ----------
    if (t < FISM_NDOCS / 4) {
        ((float4*)(out + (size_t)b * FISM_NDOCS))[t] = ((const float4*)sc)[t];
    }
}

extern "C" void kernel_launch(void* const* d_in, const int* in_sizes, int n_in,
                              void* d_out, int out_size, void* d_ws, size_t ws_size,
                              hipStream_t stream) {
    const int*   item_lst        = (const int*)d_in[0];
    const int*   past_item_lst   = (const int*)d_in[1];
    const int*   len_past_items  = (const int*)d_in[2];
    const float* item_table      = (const float*)d_in[3];
    const float* past_item_table = (const float*)d_in[4];
    const float* item_bias_table = (const float*)d_in[5];
    float*       out             = (float*)d_out;

    FISM_55284819034149_kernel<<<FISM_B, 256, 0, stream>>>(
        item_lst, past_item_lst, len_past_items,
        item_table, past_item_table, item_bias_table, out);
}